// Round 15
// baseline (193.236 us; speedup 1.0000x reference)
//
#include <hip/hip_runtime.h>
#include <cstddef>
#include <cstdint>

// ---------------------------------------------------------------------------
// GCN pipeline, fused + atomic-free CSR, fp8-gather edition:
//   out = P @ A_hat @ (relu(A_hat@(X@W1)+b1) @ U) + bb,  U=W2@Wl, bb=b2@Wl+bl
// Dispatches (8):
//   K1{U(parallel)|wtrans|gstart|hist(LDS)|convert_x(f16)} -> scanA -> scanB ->
//   K4{scatter | GEMM1(f16 MFMA 128x128, XCD-swizzled, fp8 C)} ->
//   bucket{rowptr|dinv|csr} -> AGG1(128thr, 8-wide MLP fp8 gather) -> mini -> pool
// Rules learned:
//  R3: same-address cross-XCD atomics ~300ns each — avoid funnels.
//  R4: prep-chain dispatches are ~half the runtime — fuse independent work.
//  R5: pack multiple counters into one 64-bit atomic where atomics needed.
//  R6(amended): scattered fire-and-forget atomics ~30-60ns marginal.
//  R7: single-wave dependent-scalar-load loops at grid tail hide ~100us.
//  R8: random-row gathers: FETCH floor = 8 XCDs x table bytes; fill rate caps
//      ~3.7 TB/s. Quantization feeding a mean-pool averages out: fp8 ok.
//  R9: keep wave accumulators <= 64 regs (128x128 / 4 waves) on unified file.
//  R10(amended R14): the lever is OUTSTANDING LOADS, not wave-instruction
//      count. 1-wave/node halved in-flight streams and REGRESSED (78->84).
//      Keep 2 waves/node + widen the independent-accumulator unroll instead.
//  R11: same-A-panel GEMM blocks swizzled to the same XCD (index mod 8)
//      cut redundant L2 fills of A by gx.
// ---------------------------------------------------------------------------

typedef unsigned short u16;
typedef unsigned char u8;
typedef _Float16 f16x8 __attribute__((ext_vector_type(8)));
typedef float f32x4 __attribute__((ext_vector_type(4)));
typedef float f32x2 __attribute__((ext_vector_type(2)));

__device__ __forceinline__ u16 f2h(float f) {
    union { _Float16 h; u16 u; } c; c.h = (_Float16)f; return c.u;
}
__device__ __forceinline__ float h2f(u16 v) {
    union { u16 u; _Float16 h; } c; c.u = v; return (float)c.h;
}
__device__ __forceinline__ u8 f2fp8(float v) {
    int p = __builtin_amdgcn_cvt_pk_fp8_f32(v, v, 0, false);
    return (u8)(p & 0xFF);
}

#define GLD_LDS16(g, l) __builtin_amdgcn_global_load_lds( \
    (const __attribute__((address_space(1))) unsigned int*)(const void*)(g), \
    (__attribute__((address_space(3))) unsigned int*)(void*)(l), 16, 0, 0)

#define BM 128
#define BN 128
#define BKK 32
#define SCAN_BS 1024

// ---------------------------------------------------------------------------
// K1: fused prep. Block roles (serial/odd roles FIRST, uniform bulk LAST):
//   [0, H+1):   U-row reduce: Ub[k][:] = W2[k]@Wl (block k); block H: bb
//   [+256):     wtrans W1 -> Wt1 (f16 transposed)
//   [+NB):      gstart (sorted-batch boundaries)
//   [+EB2):     LDS histogram of dst>>8 -> histG
//   [+CB):      convert_x fp32 -> f16 (uniform bulk, tail-filler)
// ---------------------------------------------------------------------------
__global__ __launch_bounds__(256) void prep_kernel(
    const int* __restrict__ dst, int* __restrict__ histG,
    const int* __restrict__ batch, int* __restrict__ gstart,
    const float* __restrict__ x, u16* __restrict__ xb,
    const float* __restrict__ W1, u16* __restrict__ Wt1,
    const float* __restrict__ W2, const float* __restrict__ Wl,
    const float* __restrict__ b2, const float* __restrict__ bl,
    u16* __restrict__ Ub, float* __restrict__ bb,
    int E, int Nn, int G, int F, int H, size_t total4,
    int EB2, int chunk, int nbuck, int CB, int NB)
{
    __shared__ float t[32][33];
    __shared__ int lhist[256];
    __shared__ float redu[256][8];
    const int b = blockIdx.x;
    const int tid = threadIdx.x;
    const int U_END = H + 1;
    const int W_END = U_END + 256;
    const int G_END = W_END + NB;
    const int HT_END = G_END + EB2;

    if (b < U_END) {
        const int k = b;
        float part[8] = {};
        for (int j = tid; j < H; j += 256) {
            const float w = (k < H) ? W2[(size_t)k * H + j] : b2[j];
#pragma unroll
            for (int o = 0; o < 8; ++o)
                part[o] = fmaf(w, Wl[j * 8 + o], part[o]);
        }
#pragma unroll
        for (int o = 0; o < 8; ++o) redu[tid][o] = part[o];
        __syncthreads();
        for (int off = 128; off > 0; off >>= 1) {
            if (tid < off)
#pragma unroll
                for (int o = 0; o < 8; ++o) redu[tid][o] += redu[tid + off][o];
            __syncthreads();
        }
        if (tid < 8) {
            if (k < H) Ub[(size_t)k * 8 + tid] = f2h(redu[0][tid]);
            else       bb[tid] = redu[0][tid] + bl[tid];
        }
    } else if (b < W_END) {
        const int wb = b - U_END;
        const int nb32 = (wb & 15) * 32, kb32 = (wb >> 4) * 32;
        const int tx = tid & 31;
        const int ty = tid >> 5;
#pragma unroll
        for (int i = 0; i < 32; i += 8)
            t[ty + i][tx] = W1[(size_t)(kb32 + ty + i) * H + nb32 + tx];
        __syncthreads();
#pragma unroll
        for (int i = 0; i < 32; i += 8)
            Wt1[(size_t)(nb32 + ty + i) * F + kb32 + tx] = f2h(t[tx][ty + i]);
    } else if (b < G_END) {
        int i = (b - W_END) * 256 + tid;
        if (i < Nn) {
            int bt = batch[i];
            int prev = (i == 0) ? -1 : batch[i - 1];
            for (int g = prev + 1; g <= bt; ++g) gstart[g] = i;
            if (i == Nn - 1)
                for (int g = bt + 1; g <= G; ++g) gstart[g] = Nn;
        }
    } else if (b < HT_END) {
        const int hb = b - G_END;
        for (int i = tid; i < nbuck; i += 256) lhist[i] = 0;
        __syncthreads();
        const int e0 = hb * chunk;
        const int e1 = min(e0 + chunk, E);
        for (int e = e0 + tid; e < e1; e += 256)
            atomicAdd(&lhist[dst[e] >> 8], 1);
        __syncthreads();
        for (int i = tid; i < nbuck; i += 256) histG[i * EB2 + hb] = lhist[i];
    } else {
        size_t i = (size_t)(b - HT_END) * 256 + tid;
        if (i < total4) {
            const float4 v = *(const float4*)(x + i * 4);
            ushort4 o;
            o.x = f2h(v.x); o.y = f2h(v.y); o.z = f2h(v.z); o.w = f2h(v.w);
            *(ushort4*)(xb + i * 4) = o;
        }
    }
}

// scanA: 1024-wide block scan of histG (T elements) -> scanG (exclusive), bsum
__global__ __launch_bounds__(1024) void scan_block_kernel(
    const int* __restrict__ in, int* __restrict__ outp, int* __restrict__ bsum, int T)
{
    __shared__ int tmp[SCAN_BS];
    const int tid = threadIdx.x;
    const int idx = blockIdx.x * SCAN_BS + tid;
    const int v = (idx < T) ? in[idx] : 0;
    tmp[tid] = v;
    __syncthreads();
    for (int off = 1; off < SCAN_BS; off <<= 1) {
        int y = (tid >= off) ? tmp[tid - off] : 0;
        __syncthreads();
        if (tid >= off) tmp[tid] += y;
        __syncthreads();
    }
    if (idx < T) outp[idx] = tmp[tid] - v;
    if (tid == SCAN_BS - 1) bsum[blockIdx.x] = tmp[tid];
}

// scanB: scan up to 128 block sums (64 threads, 2 elems each)
__global__ void scan_sums2_kernel(const int* __restrict__ bsum, int* __restrict__ boff, int nb2)
{
    const int t = threadIdx.x;
    int a = (2 * t < nb2) ? bsum[2 * t] : 0;
    int c = (2 * t + 1 < nb2) ? bsum[2 * t + 1] : 0;
    int pair = a + c;
    int v = pair;
    for (int off = 1; off < 64; off <<= 1) {
        int y = __shfl_up(v, off);
        if (t >= off) v += y;
    }
    int excl = v - pair;
    if (2 * t < nb2) boff[2 * t] = excl;
    if (2 * t + 1 < nb2) boff[2 * t + 1] = excl + a;
}

// ---------------------------------------------------------------------------
// K4: scatter (blocks [0,EB2)) | GEMM1 (blocks [EB2, EB2+GB)).
// GEMM (m97 structure, f16 in, fp8 out): 128x128 tile, 4 waves, acc[4][4].
// R11: same-m quads mapped to congruent-mod-8 indices (same XCD).
// ---------------------------------------------------------------------------
__global__ __launch_bounds__(256) void gemm_scatter_kernel(
    const u16* __restrict__ A, const u16* __restrict__ Bt, u8* __restrict__ C8,
    int M, int N, int K, int GB, int gx,
    const int* __restrict__ src, const int* __restrict__ dst,
    const float* __restrict__ ew, const int* __restrict__ scanG,
    const int* __restrict__ boff2, int2* __restrict__ bucketed,
    int E, int nbuck, int EB2, int chunk)
{
    __shared__ u16 As[BM * BKK];   // 8 KB
    __shared__ u16 Bs[BN * BKK];   // 8 KB
    const int b = blockIdx.x;
    const int tid = threadIdx.x;

    if (b < EB2) {
        // ---- scatter role (R7: odd roles first) ----
        int* lbase = (int*)As;
        int* lcnt = (int*)Bs;
        for (int i = tid; i < nbuck; i += 256) {
            int idx = i * EB2 + b;
            lbase[i] = scanG[idx] + boff2[idx >> 10];
            lcnt[i] = 0;
        }
        __syncthreads();
        const int e0 = b * chunk;
        const int e1 = min(e0 + chunk, E);
        for (int e = e0 + tid; e < e1; e += 256) {
            int d = dst[e];
            int bin = d >> 8;
            int r = atomicAdd(&lcnt[bin], 1);
            bucketed[lbase[bin] + r] = make_int2(src[e] | ((d & 255) << 16),
                                                __float_as_int(ew[e]));
        }
        return;
    }

    // ---- GEMM role ----
    const int gb = b - EB2;
    // R11 decode: index = (m%8) + n*8 + (m/8)*(8*gx); same-m quad same XCD.
    int mt_, n_, m_;
    mt_ = GB / gx;
    {
        const int full = (mt_ & ~7) * gx;
        if (gb < full) {
            const int grp = gb / (8 * gx);
            const int r = gb % (8 * gx);
            n_ = r >> 3;
            m_ = (grp << 3) + (r & 7);
        } else {
            const int tt = gb - full;
            const int rem = mt_ & 7;
            n_ = tt / rem;
            m_ = (mt_ & ~7) + tt % rem;
        }
    }
    const int lane = tid & 63;
    const int wave = tid >> 6;
    const int wr = wave >> 1, wc = wave & 1;
    const int m0 = m_ * BM;
    const int n0 = n_ * BN;

    const int srow = tid >> 2;
    const int scol = (tid & 3) * 8;

    f32x4 acc[4][4] = {};

    const u16* aptr0 = A + (size_t)(m0 + srow) * K + scol;
    const u16* aptr1 = A + (size_t)(m0 + srow + 64) * K + scol;
    const u16* bptr0 = Bt + (size_t)(n0 + srow) * K + scol;
    const u16* bptr1 = Bt + (size_t)(n0 + srow + 64) * K + scol;

    for (int k0 = 0; k0 < K; k0 += BKK) {
        GLD_LDS16(aptr0 + k0, As + (size_t)tid * 8);
        GLD_LDS16(aptr1 + k0, As + (size_t)(256 + tid) * 8);
        GLD_LDS16(bptr0 + k0, Bs + (size_t)tid * 8);
        GLD_LDS16(bptr1 + k0, Bs + (size_t)(256 + tid) * 8);
        __syncthreads();

        f16x8 af[4], bfr[4];
#pragma unroll
        for (int mi = 0; mi < 4; ++mi)
            af[mi] = *(const f16x8*)(As + (wr * 64 + mi * 16 + (lane & 15)) * BKK + (lane >> 4) * 8);
#pragma unroll
        for (int nj = 0; nj < 4; ++nj)
            bfr[nj] = *(const f16x8*)(Bs + (wc * 64 + nj * 16 + (lane & 15)) * BKK + (lane >> 4) * 8);
#pragma unroll
        for (int mi = 0; mi < 4; ++mi)
#pragma unroll
            for (int nj = 0; nj < 4; ++nj)
                acc[mi][nj] = __builtin_amdgcn_mfma_f32_16x16x32_f16(af[mi], bfr[nj], acc[mi][nj], 0, 0, 0);
        __syncthreads();
    }

    const int crow = (lane >> 4) * 4;
    const int ccol = lane & 15;
#pragma unroll
    for (int mi = 0; mi < 4; ++mi) {
        const int gr0 = m0 + wr * 64 + mi * 16 + crow;
#pragma unroll
        for (int r = 0; r < 4; ++r) {
            const int gr = gr0 + r;
            if (gr < M) {
#pragma unroll
                for (int nj = 0; nj < 4; ++nj)
                    C8[(size_t)gr * N + n0 + wc * 64 + nj * 16 + ccol] = f2fp8(acc[mi][nj][r]);
            }
        }
    }
}

// ---------------------------------------------------------------------------
// bucket build: one block per bucket (256 node slots).
// ---------------------------------------------------------------------------
__global__ __launch_bounds__(256) void bucket_kernel(
    const int2* __restrict__ bucketed, const int* __restrict__ scanG,
    const int* __restrict__ boff2, int2* __restrict__ csr,
    int* __restrict__ rowptr, float* __restrict__ dinv,
    int E, int Nn, int nbuck, int EB2)
{
    __shared__ int cnt[256];
    __shared__ unsigned int degf[256];
    __shared__ int rp[256];
    const int b = blockIdx.x;
    const int tid = threadIdx.x;
    cnt[tid] = 0;
    degf[tid] = 0;
    __syncthreads();
    const int idx0 = b * EB2;
    const int regstart = scanG[idx0] + boff2[idx0 >> 10];
    const int regend = (b + 1 < nbuck)
        ? (scanG[idx0 + EB2] + boff2[(idx0 + EB2) >> 10]) : E;
    for (int i = regstart + tid; i < regend; i += 256) {
        const int2 en = bucketed[i];
        const int dl = (en.x >> 16) & 255;
        atomicAdd(&cnt[dl], 1);
        atomicAdd(&degf[dl], (unsigned int)(__int_as_float(en.y) * 1048576.0f + 0.5f));
    }
    __syncthreads();
    const int v = cnt[tid];
    rp[tid] = v;
    __syncthreads();
    for (int off = 1; off < 256; off <<= 1) {
        int y = (tid >= off) ? rp[tid - off] : 0;
        __syncthreads();
        if (tid >= off) rp[tid] += y;
        __syncthreads();
    }
    const int excl = rp[tid] - v;
    const int node = (b << 8) + tid;
    if (node < Nn) {
        rowptr[node] = regstart + excl;
        dinv[node] = rsqrtf((float)degf[tid] * (1.0f / 1048576.0f) + 1.0f);
    }
    if (b == nbuck - 1 && tid == 0) rowptr[Nn] = E;
    __syncthreads();
    cnt[tid] = 0;
    rp[tid] = excl;
    __syncthreads();
    for (int i = regstart + tid; i < regend; i += 256) {
        const int2 en = bucketed[i];
        const int dl = (en.x >> 16) & 255;
        const int r = atomicAdd(&cnt[dl], 1);
        csr[regstart + rp[dl] + r] = make_int2(en.x & 0xFFFF, en.y);
    }
}

// ---------------------------------------------------------------------------
// AGG1 fused, 128 threads (2 waves/node), 4 fp8 cols/thread, 8-WIDE MLP:
//   h = relu(b1 + dinv^2*T1[n] + sum nr*T1[s]);  Y = h @ U.
// R10-amended: 8 independent accumulator sets keep 8 row-gathers in flight.
// ---------------------------------------------------------------------------
__global__ __launch_bounds__(128) void agg_proj_kernel(
    const u8* __restrict__ hw, const float* __restrict__ dinv,
    const int* __restrict__ rowptr, const int2* __restrict__ csr,
    const float* __restrict__ bias, const u16* __restrict__ Ub,
    float* __restrict__ Y)
{
    const int n = blockIdx.x;
    const int c = threadIdx.x * 4;           // fp8 col base (0..508)
    const float di = dinv[n];
    float4 acc[8];
#pragma unroll
    for (int u = 1; u < 8; ++u) acc[u] = make_float4(0.f, 0.f, 0.f, 0.f);
    acc[0] = *(const float4*)(bias + c);
    {
        const unsigned int hv = *(const unsigned int*)(hw + (size_t)n * 512 + c);
        const f32x2 lo = __builtin_amdgcn_cvt_pk_f32_fp8((int)hv, false);
        const f32x2 hi = __builtin_amdgcn_cvt_pk_f32_fp8((int)hv, true);
        const float s = di * di;
        acc[0].x = fmaf(s, lo[0], acc[0].x);
        acc[0].y = fmaf(s, lo[1], acc[0].y);
        acc[0].z = fmaf(s, hi[0], acc[0].z);
        acc[0].w = fmaf(s, hi[1], acc[0].w);
    }
    int i = rowptr[n];
    const int end = rowptr[n + 1];
    for (; i + 8 <= end; i += 8) {
        int2 e[8];
        unsigned int v[8];
        float nr[8];
#pragma unroll
        for (int u = 0; u < 8; ++u) e[u] = csr[i + u];
#pragma unroll
        for (int u = 0; u < 8; ++u) v[u] = *(const unsigned int*)(hw + (size_t)e[u].x * 512 + c);
#pragma unroll
        for (int u = 0; u < 8; ++u) nr[u] = dinv[e[u].x] * __int_as_float(e[u].y) * di;
#pragma unroll
        for (int u = 0; u < 8; ++u) {
            const f32x2 lo = __builtin_amdgcn_cvt_pk_f32_fp8((int)v[u], false);
            const f32x2 hi = __builtin_amdgcn_cvt_pk_f32_fp8((int)v[u], true);
            acc[u].x = fmaf(nr[u], lo[0], acc[u].x);
            acc[u].y = fmaf(nr[u], lo[1], acc[u].y);
            acc[u].z = fmaf(nr[u], hi[0], acc[u].z);
            acc[u].w = fmaf(nr[u], hi[1], acc[u].w);
        }
    }
    for (; i < end; ++i) {
        const int2 en = csr[i];
        const float nr = dinv[en.x] * __int_as_float(en.y) * di;
        const unsigned int v = *(const unsigned int*)(hw + (size_t)en.x * 512 + c);
        const f32x2 lo = __builtin_amdgcn_cvt_pk_f32_fp8((int)v, false);
        const f32x2 hi = __builtin_amdgcn_cvt_pk_f32_fp8((int)v, true);
        acc[0].x = fmaf(nr, lo[0], acc[0].x);
        acc[0].y = fmaf(nr, lo[1], acc[0].y);
        acc[0].z = fmaf(nr, hi[0], acc[0].z);
        acc[0].w = fmaf(nr, hi[1], acc[0].w);
    }
#pragma unroll
    for (int u = 1; u < 8; ++u) {
        acc[0].x += acc[u].x;
        acc[0].y += acc[u].y;
        acc[0].z += acc[u].z;
        acc[0].w += acc[u].w;
    }
    float4 h;
    h.x = fmaxf(acc[0].x, 0.f);
    h.y = fmaxf(acc[0].y, 0.f);
    h.z = fmaxf(acc[0].z, 0.f);
    h.w = fmaxf(acc[0].w, 0.f);

    float part[8];
    {
        const ushort4* up = (const ushort4*)(Ub + (size_t)c * 8);
        const ushort4 r0a = up[0], r0b = up[1];
        const ushort4 r1a = up[2], r1b = up[3];
        const ushort4 r2a = up[4], r2b = up[5];
        const ushort4 r3a = up[6], r3b = up[7];
        const u16 u0[8] = {r0a.x, r0a.y, r0a.z, r0a.w, r0b.x, r0b.y, r0b.z, r0b.w};
        const u16 u1[8] = {r1a.x, r1a.y, r1a.z, r1a.w, r1b.x, r1b.y, r1b.z, r1b.w};
        const u16 u2[8] = {r2a.x, r2a.y, r2a.z, r2a.w, r2b.x, r2b.y, r2b.z, r2b.w};
        const u16 u3[8] = {r3a.x, r3a.y, r3a.z, r3a.w, r3b.x, r3b.y, r3b.z, r3b.w};
#pragma unroll
        for (int o = 0; o < 8; ++o) {
            float p = h.x * h2f(u0[o]);
            p = fmaf(h.y, h2f(u1[o]), p);
            p = fmaf(h.z, h2f(u2[o]), p);
            p = fmaf(h.w, h2f(u3[o]), p);
            part[o] = p;
        }
    }
#pragma unroll
    for (int o = 0; o < 8; ++o) {
#pragma unroll
        for (int off = 1; off < 64; off <<= 1)
            part[o] += __shfl_xor(part[o], off);
    }
    __shared__ float red[2][8];
    const int lane = threadIdx.x & 63;
    const int wid = threadIdx.x >> 6;
    if (lane == 0)
#pragma unroll
        for (int o = 0; o < 8; ++o) red[wid][o] = part[o];
    __syncthreads();
    if (threadIdx.x < 8)
        Y[(size_t)n * 8 + threadIdx.x] = red[0][threadIdx.x] + red[1][threadIdx.x];
}

// ---------------------------------------------------------------------------
// mini-agg on 8 cols, 4-wide MLP, norm on the fly
// ---------------------------------------------------------------------------
__global__ __launch_bounds__(256) void mini_agg_kernel(
    const float* __restrict__ Y, const float* __restrict__ dinv,
    const int* __restrict__ rowptr, const int2* __restrict__ csr,
    float* __restrict__ Z, int Nn)
{
    const int t = threadIdx.x;
    const int n = blockIdx.x * 32 + (t >> 3);
    const int o = t & 7;
    if (n >= Nn) return;
    const float di = dinv[n];
    float acc = di * di * Y[(size_t)n * 8 + o];
    float a1 = 0.f, a2 = 0.f, a3 = 0.f;
    const int beg = rowptr[n];
    const int end = rowptr[n + 1];
    int i = beg;
    for (; i + 4 <= end; i += 4) {
        const int2 e0 = csr[i + 0];
        const int2 e1 = csr[i + 1];
        const int2 e2 = csr[i + 2];
        const int2 e3 = csr[i + 3];
        const float y0 = Y[(size_t)e0.x * 8 + o];
        const float y1 = Y[(size_t)e1.x * 8 + o];
        const float y2 = Y[(size_t)e2.x * 8 + o];
        const float y3 = Y[(size_t)e3.x * 8 + o];
        acc = fmaf(dinv[e0.x] * __int_as_float(e0.y) * di, y0, acc);
        a1  = fmaf(dinv[e1.x] * __int_as_float(e1.y) * di, y1, a1);
        a2  = fmaf(dinv[e2.x] * __int_as_float(e2.y) * di, y2, a2);
        a3  = fmaf(dinv[e3.x] * __int_as_float(e3.y) * di, y3, a3);
    }
    for (; i < end; ++i) {
        const int2 en = csr[i];
        acc = fmaf(dinv[en.x] * __int_as_float(en.y) * di, Y[(size_t)en.x * 8 + o], acc);
    }
    Z[(size_t)n * 8 + o] = acc + a1 + a2 + a3;
}

// ---------------------------------------------------------------------------
// per-graph mean pool + bias (no atomics)
// ---------------------------------------------------------------------------
__global__ __launch_bounds__(256) void pool8_kernel(
    const float* __restrict__ Z, const int* __restrict__ gstart,
    const float* __restrict__ bb, float* __restrict__ out)
{
    const int g = blockIdx.x;
    const int t = threadIdx.x;
    const int grp = t >> 3;
    const int o = t & 7;
    const int beg = gstart[g], end = gstart[g + 1];
    float acc = 0.f;
    for (int n = beg + grp; n < end; n += 32)
        acc += Z[(size_t)n * 8 + o];
    acc += __shfl_xor(acc, 8);
    acc += __shfl_xor(acc, 16);
    acc += __shfl_xor(acc, 32);
    __shared__ float red[4][8];
    const int lane = t & 63;
    const int wid = t >> 6;
    if (lane < 8) red[wid][lane] = acc;
    __syncthreads();
    if (t < 8) {
        const int c = end - beg;
        const float inv = 1.0f / (float)(c > 0 ? c : 1);
        out[g * 8 + t] = (red[0][t] + red[1][t] + red[2][t] + red[3][t]) * inv + bb[t];
    }
}

// ---------------------------------------------------------------------------
extern "C" void kernel_launch(void* const* d_in, const int* in_sizes, int n_in,
                              void* d_out, int out_size, void* d_ws, size_t ws_size,
                              hipStream_t stream)
{
    const float* x    = (const float*)d_in[0];
    const int*   eidx = (const int*)d_in[1];
    const int*   batch= (const int*)d_in[2];
    const float* ew   = (const float*)d_in[3];
    const float* W1   = (const float*)d_in[4];
    const float* b1   = (const float*)d_in[5];
    const float* W2   = (const float*)d_in[6];
    const float* b2   = (const float*)d_in[7];
    const float* Wl   = (const float*)d_in[8];
    const float* bl   = (const float*)d_in[9];
    float* out = (float*)d_out;

    const int Nn = in_sizes[2];            // 50000
    const int Ee = in_sizes[3];            // 800000
    const int F  = in_sizes[0] / Nn;       // 512
    const int H  = in_sizes[5];            // 512
    const int G  = 64;
    const int Mpad = (Nn + BM - 1) / BM * BM;

    const int* src = eidx;
    const int* dst = eidx + Ee;

    char* base = (char*)d_ws;
    size_t off = 0;
    auto alloc = [&](size_t bytes) -> char* {
        char* p = base + off;
        off += (bytes + 255) & ~(size_t)255;
        return p;
    };
    u16* xb  = (u16*)alloc((size_t)Mpad * F * sizeof(u16));
    u8*  hb0 = (u8*)alloc((size_t)Mpad * H * sizeof(u8));     // T1 = x@W1 (fp8)
    u16* Wt1 = (u16*)alloc((size_t)F * H * sizeof(u16));
    u16* Ub  = (u16*)alloc((size_t)H * 8 * sizeof(u16));
    float* Yb = (float*)alloc((size_t)Nn * 8 * sizeof(float));
    float* Zb = (float*)alloc((size_t)Nn * 8 * sizeof(float));
    float* bb = (float*)alloc(8 * sizeof(float));
    float* dinv = (float*)alloc((size_t)Nn * sizeof(float));
    int*   gstart  = (int*)alloc((size_t)(G + 1) * sizeof(int));
    int*   rowptr  = (int*)alloc((size_t)(Nn + 1) * sizeof(int));

    const int nbuck = (Nn + 255) >> 8;               // 196
    const int EB2 = 392;
    const int chunk = (Ee + EB2 - 1) / EB2;          // 2041
    const int T = nbuck * EB2;                       // 76832
    const int SB = (T + SCAN_BS - 1) / SCAN_BS;      // 76

    int*  histG = (int*)alloc((size_t)T * sizeof(int));
    int*  scanG = (int*)alloc((size_t)T * sizeof(int));
    int*  bsumA = (int*)alloc((size_t)SB * sizeof(int));
    int*  boff2 = (int*)alloc((size_t)SB * sizeof(int));
    int2* bucketed = (int2*)alloc((size_t)Ee * sizeof(int2));
    int2* csr      = (int2*)alloc((size_t)Ee * sizeof(int2));
    (void)ws_size;

    const size_t total4 = (size_t)Nn * F / 4;
    const int CB = (int)((total4 + 255) / 256);      // 25000
    const int NB = (Nn + 255) / 256;                 // 196
    const int K1_blocks = (H + 1) + 256 + NB + EB2 + CB;
    prep_kernel<<<K1_blocks, 256, 0, stream>>>(
        dst, histG, batch, gstart, x, xb, W1, Wt1, W2, Wl, b2, bl, Ub, bb,
        Ee, Nn, G, F, H, total4, EB2, chunk, nbuck, CB, NB);

    scan_block_kernel<<<SB, SCAN_BS, 0, stream>>>(histG, scanG, bsumA, T);
    scan_sums2_kernel<<<1, 64, 0, stream>>>(bsumA, boff2, SB);

    const int gx = H / BN;                           // 4
    const int GB = gx * (Mpad / BM);                 // 1564
    gemm_scatter_kernel<<<EB2 + GB, 256, 0, stream>>>(
        xb, Wt1, hb0, Nn, H, F, GB, gx,
        src, dst, ew, scanG, boff2, bucketed, Ee, nbuck, EB2, chunk);

    bucket_kernel<<<nbuck, 256, 0, stream>>>(bucketed, scanG, boff2, csr,
                                             rowptr, dinv, Ee, Nn, nbuck, EB2);

    agg_proj_kernel<<<Nn, 128, 0, stream>>>(hb0, dinv, rowptr, csr, b1, Ub, Yb);
    mini_agg_kernel<<<(Nn + 31) / 32, 256, 0, stream>>>(Yb, dinv, rowptr, csr, Zb, Nn);
    pool8_kernel<<<G, 256, 0, stream>>>(Zb, gstart, bb, out);
}

// Round 16
// 185.930 us; speedup vs baseline: 1.0393x; 1.0393x over previous
//
#include <hip/hip_runtime.h>
#include <cstddef>
#include <cstdint>

// ---------------------------------------------------------------------------
// GCN pipeline, fused + atomic-free CSR, fp8-gather edition (R13 config —
// empirically best at 186.3us):
//   out = P @ A_hat @ (relu(A_hat@(X@W1)+b1) @ U) + bb,  U=W2@Wl, bb=b2@Wl+bl
// Dispatches (8):
//   K1{U(parallel)|wtrans|gstart|hist(LDS)|convert_x(f16)} -> scanA -> scanB ->
//   K4{scatter | GEMM1(f16 MFMA 128x128, XCD-swizzled, fp8 C)} ->
//   bucket{rowptr|dinv|csr} -> AGG1(128thr, 4-wide MLP fp8 gather) -> mini -> pool
// Rules learned:
//  R3: same-address cross-XCD atomics ~300ns each — avoid funnels.
//  R4: prep-chain dispatches are ~half the runtime — fuse independent work.
//  R5: pack multiple counters into one 64-bit atomic where atomics needed.
//  R6(amended): scattered fire-and-forget atomics ~30-60ns marginal.
//  R7: single-wave dependent-scalar-load loops at grid tail hide ~100us.
//  R8: random-row gathers: FETCH floor = 8 XCDs x table bytes. Quantization
//      feeding a mean-pool averages out: fp8 intermediates cost ~0 error.
//  R9: keep wave accumulators <= 64 regs (128x128 / 4 waves) on unified file.
//  R10(final): 4-wide independent-accumulator MLP at 2 waves/node is the
//      empirical optimum for the 512B-row gather: 78us. 1-wave/node (fewer
//      streams) = 84us; 8-wide (occupancy+tail) = 85.8us. Latency-bound
//      basin at ~2.5 TB/s fill; fill-cap 3.7 TB/s unreachable from this
//      structure.
//  R11: same-A-panel GEMM blocks swizzled to the same XCD (index mod 8)
//      cut redundant L2 fills of A by gx.
// ---------------------------------------------------------------------------

typedef unsigned short u16;
typedef unsigned char u8;
typedef _Float16 f16x8 __attribute__((ext_vector_type(8)));
typedef float f32x4 __attribute__((ext_vector_type(4)));
typedef float f32x2 __attribute__((ext_vector_type(2)));

__device__ __forceinline__ u16 f2h(float f) {
    union { _Float16 h; u16 u; } c; c.h = (_Float16)f; return c.u;
}
__device__ __forceinline__ float h2f(u16 v) {
    union { u16 u; _Float16 h; } c; c.u = v; return (float)c.h;
}
__device__ __forceinline__ u8 f2fp8(float v) {
    int p = __builtin_amdgcn_cvt_pk_fp8_f32(v, v, 0, false);
    return (u8)(p & 0xFF);
}

#define GLD_LDS16(g, l) __builtin_amdgcn_global_load_lds( \
    (const __attribute__((address_space(1))) unsigned int*)(const void*)(g), \
    (__attribute__((address_space(3))) unsigned int*)(void*)(l), 16, 0, 0)

#define BM 128
#define BN 128
#define BKK 32
#define SCAN_BS 1024

// ---------------------------------------------------------------------------
// K1: fused prep. Block roles (serial/odd roles FIRST, uniform bulk LAST):
//   [0, H+1):   U-row reduce: Ub[k][:] = W2[k]@Wl (block k); block H: bb
//   [+256):     wtrans W1 -> Wt1 (f16 transposed)
//   [+NB):      gstart (sorted-batch boundaries)
//   [+EB2):     LDS histogram of dst>>8 -> histG
//   [+CB):      convert_x fp32 -> f16 (uniform bulk, tail-filler)
// ---------------------------------------------------------------------------
__global__ __launch_bounds__(256) void prep_kernel(
    const int* __restrict__ dst, int* __restrict__ histG,
    const int* __restrict__ batch, int* __restrict__ gstart,
    const float* __restrict__ x, u16* __restrict__ xb,
    const float* __restrict__ W1, u16* __restrict__ Wt1,
    const float* __restrict__ W2, const float* __restrict__ Wl,
    const float* __restrict__ b2, const float* __restrict__ bl,
    u16* __restrict__ Ub, float* __restrict__ bb,
    int E, int Nn, int G, int F, int H, size_t total4,
    int EB2, int chunk, int nbuck, int CB, int NB)
{
    __shared__ float t[32][33];
    __shared__ int lhist[256];
    __shared__ float redu[256][8];
    const int b = blockIdx.x;
    const int tid = threadIdx.x;
    const int U_END = H + 1;
    const int W_END = U_END + 256;
    const int G_END = W_END + NB;
    const int HT_END = G_END + EB2;

    if (b < U_END) {
        const int k = b;
        float part[8] = {};
        for (int j = tid; j < H; j += 256) {
            const float w = (k < H) ? W2[(size_t)k * H + j] : b2[j];
#pragma unroll
            for (int o = 0; o < 8; ++o)
                part[o] = fmaf(w, Wl[j * 8 + o], part[o]);
        }
#pragma unroll
        for (int o = 0; o < 8; ++o) redu[tid][o] = part[o];
        __syncthreads();
        for (int off = 128; off > 0; off >>= 1) {
            if (tid < off)
#pragma unroll
                for (int o = 0; o < 8; ++o) redu[tid][o] += redu[tid + off][o];
            __syncthreads();
        }
        if (tid < 8) {
            if (k < H) Ub[(size_t)k * 8 + tid] = f2h(redu[0][tid]);
            else       bb[tid] = redu[0][tid] + bl[tid];
        }
    } else if (b < W_END) {
        const int wb = b - U_END;
        const int nb32 = (wb & 15) * 32, kb32 = (wb >> 4) * 32;
        const int tx = tid & 31;
        const int ty = tid >> 5;
#pragma unroll
        for (int i = 0; i < 32; i += 8)
            t[ty + i][tx] = W1[(size_t)(kb32 + ty + i) * H + nb32 + tx];
        __syncthreads();
#pragma unroll
        for (int i = 0; i < 32; i += 8)
            Wt1[(size_t)(nb32 + ty + i) * F + kb32 + tx] = f2h(t[tx][ty + i]);
    } else if (b < G_END) {
        int i = (b - W_END) * 256 + tid;
        if (i < Nn) {
            int bt = batch[i];
            int prev = (i == 0) ? -1 : batch[i - 1];
            for (int g = prev + 1; g <= bt; ++g) gstart[g] = i;
            if (i == Nn - 1)
                for (int g = bt + 1; g <= G; ++g) gstart[g] = Nn;
        }
    } else if (b < HT_END) {
        const int hb = b - G_END;
        for (int i = tid; i < nbuck; i += 256) lhist[i] = 0;
        __syncthreads();
        const int e0 = hb * chunk;
        const int e1 = min(e0 + chunk, E);
        for (int e = e0 + tid; e < e1; e += 256)
            atomicAdd(&lhist[dst[e] >> 8], 1);
        __syncthreads();
        for (int i = tid; i < nbuck; i += 256) histG[i * EB2 + hb] = lhist[i];
    } else {
        size_t i = (size_t)(b - HT_END) * 256 + tid;
        if (i < total4) {
            const float4 v = *(const float4*)(x + i * 4);
            ushort4 o;
            o.x = f2h(v.x); o.y = f2h(v.y); o.z = f2h(v.z); o.w = f2h(v.w);
            *(ushort4*)(xb + i * 4) = o;
        }
    }
}

// scanA: 1024-wide block scan of histG (T elements) -> scanG (exclusive), bsum
__global__ __launch_bounds__(1024) void scan_block_kernel(
    const int* __restrict__ in, int* __restrict__ outp, int* __restrict__ bsum, int T)
{
    __shared__ int tmp[SCAN_BS];
    const int tid = threadIdx.x;
    const int idx = blockIdx.x * SCAN_BS + tid;
    const int v = (idx < T) ? in[idx] : 0;
    tmp[tid] = v;
    __syncthreads();
    for (int off = 1; off < SCAN_BS; off <<= 1) {
        int y = (tid >= off) ? tmp[tid - off] : 0;
        __syncthreads();
        if (tid >= off) tmp[tid] += y;
        __syncthreads();
    }
    if (idx < T) outp[idx] = tmp[tid] - v;
    if (tid == SCAN_BS - 1) bsum[blockIdx.x] = tmp[tid];
}

// scanB: scan up to 128 block sums (64 threads, 2 elems each)
__global__ void scan_sums2_kernel(const int* __restrict__ bsum, int* __restrict__ boff, int nb2)
{
    const int t = threadIdx.x;
    int a = (2 * t < nb2) ? bsum[2 * t] : 0;
    int c = (2 * t + 1 < nb2) ? bsum[2 * t + 1] : 0;
    int pair = a + c;
    int v = pair;
    for (int off = 1; off < 64; off <<= 1) {
        int y = __shfl_up(v, off);
        if (t >= off) v += y;
    }
    int excl = v - pair;
    if (2 * t < nb2) boff[2 * t] = excl;
    if (2 * t + 1 < nb2) boff[2 * t + 1] = excl + a;
}

// ---------------------------------------------------------------------------
// K4: scatter (blocks [0,EB2)) | GEMM1 (blocks [EB2, EB2+GB)).
// GEMM (m97 structure, f16 in, fp8 out): 128x128 tile, 4 waves, acc[4][4].
// R11: same-m quads mapped to congruent-mod-8 indices (same XCD).
// ---------------------------------------------------------------------------
__global__ __launch_bounds__(256) void gemm_scatter_kernel(
    const u16* __restrict__ A, const u16* __restrict__ Bt, u8* __restrict__ C8,
    int M, int N, int K, int GB, int gx,
    const int* __restrict__ src, const int* __restrict__ dst,
    const float* __restrict__ ew, const int* __restrict__ scanG,
    const int* __restrict__ boff2, int2* __restrict__ bucketed,
    int E, int nbuck, int EB2, int chunk)
{
    __shared__ u16 As[BM * BKK];   // 8 KB
    __shared__ u16 Bs[BN * BKK];   // 8 KB
    const int b = blockIdx.x;
    const int tid = threadIdx.x;

    if (b < EB2) {
        // ---- scatter role (R7: odd roles first) ----
        int* lbase = (int*)As;
        int* lcnt = (int*)Bs;
        for (int i = tid; i < nbuck; i += 256) {
            int idx = i * EB2 + b;
            lbase[i] = scanG[idx] + boff2[idx >> 10];
            lcnt[i] = 0;
        }
        __syncthreads();
        const int e0 = b * chunk;
        const int e1 = min(e0 + chunk, E);
        for (int e = e0 + tid; e < e1; e += 256) {
            int d = dst[e];
            int bin = d >> 8;
            int r = atomicAdd(&lcnt[bin], 1);
            bucketed[lbase[bin] + r] = make_int2(src[e] | ((d & 255) << 16),
                                                __float_as_int(ew[e]));
        }
        return;
    }

    // ---- GEMM role ----
    const int gb = b - EB2;
    // R11 decode: index = (m%8) + n*8 + (m/8)*(8*gx); same-m quad same XCD.
    int mt_, n_, m_;
    mt_ = GB / gx;
    {
        const int full = (mt_ & ~7) * gx;
        if (gb < full) {
            const int grp = gb / (8 * gx);
            const int r = gb % (8 * gx);
            n_ = r >> 3;
            m_ = (grp << 3) + (r & 7);
        } else {
            const int tt = gb - full;
            const int rem = mt_ & 7;
            n_ = tt / rem;
            m_ = (mt_ & ~7) + tt % rem;
        }
    }
    const int lane = tid & 63;
    const int wave = tid >> 6;
    const int wr = wave >> 1, wc = wave & 1;
    const int m0 = m_ * BM;
    const int n0 = n_ * BN;

    const int srow = tid >> 2;
    const int scol = (tid & 3) * 8;

    f32x4 acc[4][4] = {};

    const u16* aptr0 = A + (size_t)(m0 + srow) * K + scol;
    const u16* aptr1 = A + (size_t)(m0 + srow + 64) * K + scol;
    const u16* bptr0 = Bt + (size_t)(n0 + srow) * K + scol;
    const u16* bptr1 = Bt + (size_t)(n0 + srow + 64) * K + scol;

    for (int k0 = 0; k0 < K; k0 += BKK) {
        GLD_LDS16(aptr0 + k0, As + (size_t)tid * 8);
        GLD_LDS16(aptr1 + k0, As + (size_t)(256 + tid) * 8);
        GLD_LDS16(bptr0 + k0, Bs + (size_t)tid * 8);
        GLD_LDS16(bptr1 + k0, Bs + (size_t)(256 + tid) * 8);
        __syncthreads();

        f16x8 af[4], bfr[4];
#pragma unroll
        for (int mi = 0; mi < 4; ++mi)
            af[mi] = *(const f16x8*)(As + (wr * 64 + mi * 16 + (lane & 15)) * BKK + (lane >> 4) * 8);
#pragma unroll
        for (int nj = 0; nj < 4; ++nj)
            bfr[nj] = *(const f16x8*)(Bs + (wc * 64 + nj * 16 + (lane & 15)) * BKK + (lane >> 4) * 8);
#pragma unroll
        for (int mi = 0; mi < 4; ++mi)
#pragma unroll
            for (int nj = 0; nj < 4; ++nj)
                acc[mi][nj] = __builtin_amdgcn_mfma_f32_16x16x32_f16(af[mi], bfr[nj], acc[mi][nj], 0, 0, 0);
        __syncthreads();
    }

    const int crow = (lane >> 4) * 4;
    const int ccol = lane & 15;
#pragma unroll
    for (int mi = 0; mi < 4; ++mi) {
        const int gr0 = m0 + wr * 64 + mi * 16 + crow;
#pragma unroll
        for (int r = 0; r < 4; ++r) {
            const int gr = gr0 + r;
            if (gr < M) {
#pragma unroll
                for (int nj = 0; nj < 4; ++nj)
                    C8[(size_t)gr * N + n0 + wc * 64 + nj * 16 + ccol] = f2fp8(acc[mi][nj][r]);
            }
        }
    }
}

// ---------------------------------------------------------------------------
// bucket build: one block per bucket (256 node slots).
// ---------------------------------------------------------------------------
__global__ __launch_bounds__(256) void bucket_kernel(
    const int2* __restrict__ bucketed, const int* __restrict__ scanG,
    const int* __restrict__ boff2, int2* __restrict__ csr,
    int* __restrict__ rowptr, float* __restrict__ dinv,
    int E, int Nn, int nbuck, int EB2)
{
    __shared__ int cnt[256];
    __shared__ unsigned int degf[256];
    __shared__ int rp[256];
    const int b = blockIdx.x;
    const int tid = threadIdx.x;
    cnt[tid] = 0;
    degf[tid] = 0;
    __syncthreads();
    const int idx0 = b * EB2;
    const int regstart = scanG[idx0] + boff2[idx0 >> 10];
    const int regend = (b + 1 < nbuck)
        ? (scanG[idx0 + EB2] + boff2[(idx0 + EB2) >> 10]) : E;
    for (int i = regstart + tid; i < regend; i += 256) {
        const int2 en = bucketed[i];
        const int dl = (en.x >> 16) & 255;
        atomicAdd(&cnt[dl], 1);
        atomicAdd(&degf[dl], (unsigned int)(__int_as_float(en.y) * 1048576.0f + 0.5f));
    }
    __syncthreads();
    const int v = cnt[tid];
    rp[tid] = v;
    __syncthreads();
    for (int off = 1; off < 256; off <<= 1) {
        int y = (tid >= off) ? rp[tid - off] : 0;
        __syncthreads();
        if (tid >= off) rp[tid] += y;
        __syncthreads();
    }
    const int excl = rp[tid] - v;
    const int node = (b << 8) + tid;
    if (node < Nn) {
        rowptr[node] = regstart + excl;
        dinv[node] = rsqrtf((float)degf[tid] * (1.0f / 1048576.0f) + 1.0f);
    }
    if (b == nbuck - 1 && tid == 0) rowptr[Nn] = E;
    __syncthreads();
    cnt[tid] = 0;
    rp[tid] = excl;
    __syncthreads();
    for (int i = regstart + tid; i < regend; i += 256) {
        const int2 en = bucketed[i];
        const int dl = (en.x >> 16) & 255;
        const int r = atomicAdd(&cnt[dl], 1);
        csr[regstart + rp[dl] + r] = make_int2(en.x & 0xFFFF, en.y);
    }
}

// ---------------------------------------------------------------------------
// AGG1 fused, 128 threads, 4 fp8 cols/thread, 4-wide MLP (R10-final optimum):
//   h = relu(b1 + dinv^2*T1[n] + sum nr*T1[s]);  Y = h @ U.
// ---------------------------------------------------------------------------
__global__ __launch_bounds__(128) void agg_proj_kernel(
    const u8* __restrict__ hw, const float* __restrict__ dinv,
    const int* __restrict__ rowptr, const int2* __restrict__ csr,
    const float* __restrict__ bias, const u16* __restrict__ Ub,
    float* __restrict__ Y)
{
    const int n = blockIdx.x;
    const int c = threadIdx.x * 4;
    const float di = dinv[n];
    float4 acc = *(const float4*)(bias + c);
    {
        const float s = di * di;
        const unsigned int hv = *(const unsigned int*)(hw + (size_t)n * 512 + c);
        const f32x2 lo = __builtin_amdgcn_cvt_pk_f32_fp8((int)hv, false);
        const f32x2 hi = __builtin_amdgcn_cvt_pk_f32_fp8((int)hv, true);
        acc.x = fmaf(s, lo[0], acc.x);
        acc.y = fmaf(s, lo[1], acc.y);
        acc.z = fmaf(s, hi[0], acc.z);
        acc.w = fmaf(s, hi[1], acc.w);
    }
    const int beg = rowptr[n];
    const int end = rowptr[n + 1];
    float4 a1 = make_float4(0.f, 0.f, 0.f, 0.f);
    float4 a2 = make_float4(0.f, 0.f, 0.f, 0.f);
    float4 a3 = make_float4(0.f, 0.f, 0.f, 0.f);
    int i = beg;
    for (; i + 4 <= end; i += 4) {
        const int2 e0 = csr[i + 0];
        const int2 e1 = csr[i + 1];
        const int2 e2 = csr[i + 2];
        const int2 e3 = csr[i + 3];
        const float d0 = dinv[e0.x], d1 = dinv[e1.x], d2 = dinv[e2.x], d3 = dinv[e3.x];
        const unsigned int v0 = *(const unsigned int*)(hw + (size_t)e0.x * 512 + c);
        const unsigned int v1 = *(const unsigned int*)(hw + (size_t)e1.x * 512 + c);
        const unsigned int v2 = *(const unsigned int*)(hw + (size_t)e2.x * 512 + c);
        const unsigned int v3 = *(const unsigned int*)(hw + (size_t)e3.x * 512 + c);
        const float n0 = d0 * __int_as_float(e0.y) * di;
        const float n1 = d1 * __int_as_float(e1.y) * di;
        const float n2 = d2 * __int_as_float(e2.y) * di;
        const float n3 = d3 * __int_as_float(e3.y) * di;
        {
            const f32x2 lo = __builtin_amdgcn_cvt_pk_f32_fp8((int)v0, false);
            const f32x2 hi = __builtin_amdgcn_cvt_pk_f32_fp8((int)v0, true);
            acc.x = fmaf(n0, lo[0], acc.x);
            acc.y = fmaf(n0, lo[1], acc.y);
            acc.z = fmaf(n0, hi[0], acc.z);
            acc.w = fmaf(n0, hi[1], acc.w);
        }
        {
            const f32x2 lo = __builtin_amdgcn_cvt_pk_f32_fp8((int)v1, false);
            const f32x2 hi = __builtin_amdgcn_cvt_pk_f32_fp8((int)v1, true);
            a1.x = fmaf(n1, lo[0], a1.x);
            a1.y = fmaf(n1, lo[1], a1.y);
            a1.z = fmaf(n1, hi[0], a1.z);
            a1.w = fmaf(n1, hi[1], a1.w);
        }
        {
            const f32x2 lo = __builtin_amdgcn_cvt_pk_f32_fp8((int)v2, false);
            const f32x2 hi = __builtin_amdgcn_cvt_pk_f32_fp8((int)v2, true);
            a2.x = fmaf(n2, lo[0], a2.x);
            a2.y = fmaf(n2, lo[1], a2.y);
            a2.z = fmaf(n2, hi[0], a2.z);
            a2.w = fmaf(n2, hi[1], a2.w);
        }
        {
            const f32x2 lo = __builtin_amdgcn_cvt_pk_f32_fp8((int)v3, false);
            const f32x2 hi = __builtin_amdgcn_cvt_pk_f32_fp8((int)v3, true);
            a3.x = fmaf(n3, lo[0], a3.x);
            a3.y = fmaf(n3, lo[1], a3.y);
            a3.z = fmaf(n3, hi[0], a3.z);
            a3.w = fmaf(n3, hi[1], a3.w);
        }
    }
    for (; i < end; ++i) {
        const int2 en = csr[i];
        const float nr = dinv[en.x] * __int_as_float(en.y) * di;
        const unsigned int v = *(const unsigned int*)(hw + (size_t)en.x * 512 + c);
        const f32x2 lo = __builtin_amdgcn_cvt_pk_f32_fp8((int)v, false);
        const f32x2 hi = __builtin_amdgcn_cvt_pk_f32_fp8((int)v, true);
        acc.x = fmaf(nr, lo[0], acc.x);
        acc.y = fmaf(nr, lo[1], acc.y);
        acc.z = fmaf(nr, hi[0], acc.z);
        acc.w = fmaf(nr, hi[1], acc.w);
    }
    acc.x += a1.x + a2.x + a3.x;
    acc.y += a1.y + a2.y + a3.y;
    acc.z += a1.z + a2.z + a3.z;
    acc.w += a1.w + a2.w + a3.w;
    acc.x = fmaxf(acc.x, 0.f);
    acc.y = fmaxf(acc.y, 0.f);
    acc.z = fmaxf(acc.z, 0.f);
    acc.w = fmaxf(acc.w, 0.f);

    float part[8];
    {
        const ushort4* up = (const ushort4*)(Ub + (size_t)c * 8);
        const ushort4 r0a = up[0], r0b = up[1];
        const ushort4 r1a = up[2], r1b = up[3];
        const ushort4 r2a = up[4], r2b = up[5];
        const ushort4 r3a = up[6], r3b = up[7];
        const u16 u0[8] = {r0a.x, r0a.y, r0a.z, r0a.w, r0b.x, r0b.y, r0b.z, r0b.w};
        const u16 u1[8] = {r1a.x, r1a.y, r1a.z, r1a.w, r1b.x, r1b.y, r1b.z, r1b.w};
        const u16 u2[8] = {r2a.x, r2a.y, r2a.z, r2a.w, r2b.x, r2b.y, r2b.z, r2b.w};
        const u16 u3[8] = {r3a.x, r3a.y, r3a.z, r3a.w, r3b.x, r3b.y, r3b.z, r3b.w};
#pragma unroll
        for (int o = 0; o < 8; ++o) {
            float p = acc.x * h2f(u0[o]);
            p = fmaf(acc.y, h2f(u1[o]), p);
            p = fmaf(acc.z, h2f(u2[o]), p);
            p = fmaf(acc.w, h2f(u3[o]), p);
            part[o] = p;
        }
    }
#pragma unroll
    for (int o = 0; o < 8; ++o) {
#pragma unroll
        for (int off = 1; off < 64; off <<= 1)
            part[o] += __shfl_xor(part[o], off);
    }
    __shared__ float red[2][8];
    const int lane = threadIdx.x & 63;
    const int wid = threadIdx.x >> 6;
    if (lane == 0)
#pragma unroll
        for (int o = 0; o < 8; ++o) red[wid][o] = part[o];
    __syncthreads();
    if (threadIdx.x < 8)
        Y[(size_t)n * 8 + threadIdx.x] = red[0][threadIdx.x] + red[1][threadIdx.x];
}

// ---------------------------------------------------------------------------
// mini-agg on 8 cols, 4-wide MLP, norm on the fly
// ---------------------------------------------------------------------------
__global__ __launch_bounds__(256) void mini_agg_kernel(
    const float* __restrict__ Y, const float* __restrict__ dinv,
    const int* __restrict__ rowptr, const int2* __restrict__ csr,
    float* __restrict__ Z, int Nn)
{
    const int t = threadIdx.x;
    const int n = blockIdx.x * 32 + (t >> 3);
    const int o = t & 7;
    if (n >= Nn) return;
    const float di = dinv[n];
    float acc = di * di * Y[(size_t)n * 8 + o];
    float a1 = 0.f, a2 = 0.f, a3 = 0.f;
    const int beg = rowptr[n];
    const int end = rowptr[n + 1];
    int i = beg;
    for (; i + 4 <= end; i += 4) {
        const int2 e0 = csr[i + 0];
        const int2 e1 = csr[i + 1];
        const int2 e2 = csr[i + 2];
        const int2 e3 = csr[i + 3];
        const float y0 = Y[(size_t)e0.x * 8 + o];
        const float y1 = Y[(size_t)e1.x * 8 + o];
        const float y2 = Y[(size_t)e2.x * 8 + o];
        const float y3 = Y[(size_t)e3.x * 8 + o];
        acc = fmaf(dinv[e0.x] * __int_as_float(e0.y) * di, y0, acc);
        a1  = fmaf(dinv[e1.x] * __int_as_float(e1.y) * di, y1, a1);
        a2  = fmaf(dinv[e2.x] * __int_as_float(e2.y) * di, y2, a2);
        a3  = fmaf(dinv[e3.x] * __int_as_float(e3.y) * di, y3, a3);
    }
    for (; i < end; ++i) {
        const int2 en = csr[i];
        acc = fmaf(dinv[en.x] * __int_as_float(en.y) * di, Y[(size_t)en.x * 8 + o], acc);
    }
    Z[(size_t)n * 8 + o] = acc + a1 + a2 + a3;
}

// ---------------------------------------------------------------------------
// per-graph mean pool + bias (no atomics)
// ---------------------------------------------------------------------------
__global__ __launch_bounds__(256) void pool8_kernel(
    const float* __restrict__ Z, const int* __restrict__ gstart,
    const float* __restrict__ bb, float* __restrict__ out)
{
    const int g = blockIdx.x;
    const int t = threadIdx.x;
    const int grp = t >> 3;
    const int o = t & 7;
    const int beg = gstart[g], end = gstart[g + 1];
    float acc = 0.f;
    for (int n = beg + grp; n < end; n += 32)
        acc += Z[(size_t)n * 8 + o];
    acc += __shfl_xor(acc, 8);
    acc += __shfl_xor(acc, 16);
    acc += __shfl_xor(acc, 32);
    __shared__ float red[4][8];
    const int lane = t & 63;
    const int wid = t >> 6;
    if (lane < 8) red[wid][lane] = acc;
    __syncthreads();
    if (t < 8) {
        const int c = end - beg;
        const float inv = 1.0f / (float)(c > 0 ? c : 1);
        out[g * 8 + t] = (red[0][t] + red[1][t] + red[2][t] + red[3][t]) * inv + bb[t];
    }
}

// ---------------------------------------------------------------------------
extern "C" void kernel_launch(void* const* d_in, const int* in_sizes, int n_in,
                              void* d_out, int out_size, void* d_ws, size_t ws_size,
                              hipStream_t stream)
{
    const float* x    = (const float*)d_in[0];
    const int*   eidx = (const int*)d_in[1];
    const int*   batch= (const int*)d_in[2];
    const float* ew   = (const float*)d_in[3];
    const float* W1   = (const float*)d_in[4];
    const float* b1   = (const float*)d_in[5];
    const float* W2   = (const float*)d_in[6];
    const float* b2   = (const float*)d_in[7];
    const float* Wl   = (const float*)d_in[8];
    const float* bl   = (const float*)d_in[9];
    float* out = (float*)d_out;

    const int Nn = in_sizes[2];            // 50000
    const int Ee = in_sizes[3];            // 800000
    const int F  = in_sizes[0] / Nn;       // 512
    const int H  = in_sizes[5];            // 512
    const int G  = 64;
    const int Mpad = (Nn + BM - 1) / BM * BM;

    const int* src = eidx;
    const int* dst = eidx + Ee;

    char* base = (char*)d_ws;
    size_t off = 0;
    auto alloc = [&](size_t bytes) -> char* {
        char* p = base + off;
        off += (bytes + 255) & ~(size_t)255;
        return p;
    };
    u16* xb  = (u16*)alloc((size_t)Mpad * F * sizeof(u16));
    u8*  hb0 = (u8*)alloc((size_t)Mpad * H * sizeof(u8));     // T1 = x@W1 (fp8)
    u16* Wt1 = (u16*)alloc((size_t)F * H * sizeof(u16));
    u16* Ub  = (u16*)alloc((size_t)H * 8 * sizeof(u16));
    float* Yb = (float*)alloc((size_t)Nn * 8 * sizeof(float));
    float* Zb = (float*)alloc((size_t)Nn * 8 * sizeof(float));
    float* bb = (float*)alloc(8 * sizeof(float));
    float* dinv = (float*)alloc((size_t)Nn * sizeof(float));
    int*   gstart  = (int*)alloc((size_t)(G + 1) * sizeof(int));
    int*   rowptr  = (int*)alloc((size_t)(Nn + 1) * sizeof(int));

    const int nbuck = (Nn + 255) >> 8;               // 196
    const int EB2 = 392;
    const int chunk = (Ee + EB2 - 1) / EB2;          // 2041
    const int T = nbuck * EB2;                       // 76832
    const int SB = (T + SCAN_BS - 1) / SCAN_BS;      // 76

    int*  histG = (int*)alloc((size_t)T * sizeof(int));
    int*  scanG = (int*)alloc((size_t)T * sizeof(int));
    int*  bsumA = (int*)alloc((size_t)SB * sizeof(int));
    int*  boff2 = (int*)alloc((size_t)SB * sizeof(int));
    int2* bucketed = (int2*)alloc((size_t)Ee * sizeof(int2));
    int2* csr      = (int2*)alloc((size_t)Ee * sizeof(int2));
    (void)ws_size;

    const size_t total4 = (size_t)Nn * F / 4;
    const int CB = (int)((total4 + 255) / 256);      // 25000
    const int NB = (Nn + 255) / 256;                 // 196
    const int K1_blocks = (H + 1) + 256 + NB + EB2 + CB;
    prep_kernel<<<K1_blocks, 256, 0, stream>>>(
        dst, histG, batch, gstart, x, xb, W1, Wt1, W2, Wl, b2, bl, Ub, bb,
        Ee, Nn, G, F, H, total4, EB2, chunk, nbuck, CB, NB);

    scan_block_kernel<<<SB, SCAN_BS, 0, stream>>>(histG, scanG, bsumA, T);
    scan_sums2_kernel<<<1, 64, 0, stream>>>(bsumA, boff2, SB);

    const int gx = H / BN;                           // 4
    const int GB = gx * (Mpad / BM);                 // 1564
    gemm_scatter_kernel<<<EB2 + GB, 256, 0, stream>>>(
        xb, Wt1, hb0, Nn, H, F, GB, gx,
        src, dst, ew, scanG, boff2, bucketed, Ee, nbuck, EB2, chunk);

    bucket_kernel<<<nbuck, 256, 0, stream>>>(bucketed, scanG, boff2, csr,
                                             rowptr, dinv, Ee, Nn, nbuck, EB2);

    agg_proj_kernel<<<Nn, 128, 0, stream>>>(hb0, dinv, rowptr, csr, b1, Ub, Yb);
    mini_agg_kernel<<<(Nn + 31) / 32, 256, 0, stream>>>(Yb, dinv, rowptr, csr, Zb, Nn);
    pool8_kernel<<<G, 256, 0, stream>>>(Zb, gstart, bb, out);
}